// Round 8
// baseline (206.306 us; speedup 1.0000x reference)
//
#include <hip/hip_runtime.h>
#include <math.h>

#define NN 4096
#define NFEAT 512
#define NHID 60
#define NCLASS 4
#define CAP 96        // per-row CSR capacity (mean ~8.2, statistical max ~22)
#define GSTRIDE 64    // padded hidden-state row stride
#define SCAN_BLKS 2048
#define SCAN_THREADS (SCAN_BLKS * 256)   // 524288 threads, 8 float4 each
#define LQ_CAP 512    // per-block LDS edge queue (expected ~16/block)
#define XW_BLKS (NN / 4)                 // 1024
#define EDGE_BLKS 256                    // 65536 threads for ~33.5K edges

// ---- stage A: stream adj, compact edge ids into global queue --------------
// Hot loop exposes only LDS atomics (~30cyc); the expensive per-edge chains
// (P gather, global atomics) are deferred to k_edges where they parallelize.
__global__ __launch_bounds__(256) void k_scan(const float* __restrict__ adj,
                                              int* __restrict__ qn,
                                              int* __restrict__ equeue) {
    __shared__ int lq[LQ_CAP];
    __shared__ int lcnt, gbase;
    if (threadIdx.x == 0) lcnt = 0;
    __syncthreads();
    const int t = blockIdx.x * 256 + threadIdx.x;
    const float4* adj4 = (const float4*)adj;
    #pragma unroll
    for (int m = 0; m < 8; ++m) {
        const int v = m * SCAN_THREADS + t;          // coalesced per pass
        const float4 a = adj4[v];
        if (a.x + a.y + a.z + a.w != 0.f) {          // adj is {0,1}
            const float av[4] = {a.x, a.y, a.z, a.w};
            #pragma unroll
            for (int q = 0; q < 4; ++q) {
                if (av[q] != 0.f) {
                    const int pos = atomicAdd(&lcnt, 1);   // LDS atomic: cheap
                    if (pos < LQ_CAP) lq[pos] = v * 4 + q;
                }
            }
        }
    }
    __syncthreads();
    if (threadIdx.x == 0) gbase = atomicAdd(qn, lcnt);     // 1 global atomic/block
    __syncthreads();
    const int n = min(lcnt, LQ_CAP);
    for (int k = threadIdx.x; k < n; k += 256)
        equeue[gbase + k] = lq[k];                         // coalesced flush
}

// ---- stage B: [0..1023] G1 = x@W1; [1024..1279] process queued edges ------
__global__ __launch_bounds__(256) void k_edges_xw(const float* __restrict__ P,
                                                  const int* __restrict__ qn,
                                                  const int* __restrict__ equeue,
                                                  float* __restrict__ dcol,
                                                  int* __restrict__ cnt,
                                                  int* __restrict__ cols,
                                                  float* __restrict__ vals,
                                                  const float* __restrict__ x,
                                                  const float* __restrict__ W1,
                                                  float* __restrict__ g1) {
    if (blockIdx.x >= XW_BLKS) {
        // ---- edges: one independent latency chain per thread --------------
        const int gtid = (blockIdx.x - XW_BLKS) * 256 + threadIdx.x;
        const int total = qn[0];
        for (int idx = gtid; idx < total; idx += EDGE_BLKS * 256) {
            const int e = equeue[idx];
            const int i = e >> 12;
            const int j = e & (NN - 1);
            const int hi = i > j ? i : j;
            const int lo = i > j ? j : i;
            const float pv = P[((hi * (hi + 1)) >> 1) + lo];
            const float s = 1.f / (1.f + __expf(-pv));     // sigmoid (adj==1)
            atomicAdd(&dcol[j], s);
            const int pos = atomicAdd(&cnt[i], 1);
            if (pos < CAP) { cols[i * CAP + pos] = j; vals[i * CAP + pos] = s; }
        }
    } else {
        // ---- xw: 4 rows/block, K split over 4 waves ------------------------
        __shared__ float part[1024];
        const int tid = threadIdx.x;
        const int w = tid >> 6, lane = tid & 63;
        const int c = lane < NHID ? lane : 0;
        const int row0 = blockIdx.x * 4;
        const int k0 = w * (NFEAT / 4);
        const float* x0 = x + (row0 + 0) * NFEAT;
        const float* x1 = x + (row0 + 1) * NFEAT;
        const float* x2 = x + (row0 + 2) * NFEAT;
        const float* x3 = x + (row0 + 3) * NFEAT;
        float a0 = 0.f, a1 = 0.f, a2 = 0.f, a3 = 0.f;
        for (int k = k0; k < k0 + NFEAT / 4; k += 4) {
            const float4 xv0 = *(const float4*)(x0 + k);   // wave-uniform 16B
            const float4 xv1 = *(const float4*)(x1 + k);
            const float4 xv2 = *(const float4*)(x2 + k);
            const float4 xv3 = *(const float4*)(x3 + k);
            const float w0 = W1[(k + 0) * NHID + c];       // lane-varying, L2-hot
            const float w1 = W1[(k + 1) * NHID + c];
            const float w2 = W1[(k + 2) * NHID + c];
            const float w3 = W1[(k + 3) * NHID + c];
            a0 = fmaf(xv0.x, w0, fmaf(xv0.y, w1, fmaf(xv0.z, w2, fmaf(xv0.w, w3, a0))));
            a1 = fmaf(xv1.x, w0, fmaf(xv1.y, w1, fmaf(xv1.z, w2, fmaf(xv1.w, w3, a1))));
            a2 = fmaf(xv2.x, w0, fmaf(xv2.y, w1, fmaf(xv2.z, w2, fmaf(xv2.w, w3, a2))));
            a3 = fmaf(xv3.x, w0, fmaf(xv3.y, w1, fmaf(xv3.z, w2, fmaf(xv3.w, w3, a3))));
        }
        part[(w * 4 + 0) * 64 + lane] = a0;
        part[(w * 4 + 1) * 64 + lane] = a1;
        part[(w * 4 + 2) * 64 + lane] = a2;
        part[(w * 4 + 3) * 64 + lane] = a3;
        __syncthreads();
        const float o = part[(0 * 4 + w) * 64 + lane] + part[(1 * 4 + w) * 64 + lane]
                      + part[(2 * 4 + w) * 64 + lane] + part[(3 * 4 + w) * 64 + lane];
        g1[(row0 + w) * GSTRIDE + lane] = (lane < NHID) ? o : 0.f;
    }
}

// ---- spmm edge accumulation, 4-batched for MLP ----------------------------
__device__ __forceinline__ float spmm_row(const float* __restrict__ gin,
                                          const float* __restrict__ dcol,
                                          const int* __restrict__ cnt,
                                          const int* __restrict__ cols,
                                          const float* __restrict__ vals,
                                          int i, int lane, float di) {
    const int nn = min(cnt[i], CAP);
    float acc = gin[i * GSTRIDE + lane] * di;   // self-loop term
    const int4*   c4 = (const int4*)(cols + i * CAP);
    const float4* v4 = (const float4*)(vals + i * CAP);
    int e = 0;
    for (; e + 4 <= nn; e += 4) {
        const int4   jj = c4[e >> 2];
        const float4 vv = v4[e >> 2];
        const float f0 = vv.x * rsqrtf(1.f + dcol[jj.x]);
        const float f1 = vv.y * rsqrtf(1.f + dcol[jj.y]);
        const float f2 = vv.z * rsqrtf(1.f + dcol[jj.z]);
        const float f3 = vv.w * rsqrtf(1.f + dcol[jj.w]);
        const float g0 = gin[jj.x * GSTRIDE + lane];
        const float g1 = gin[jj.y * GSTRIDE + lane];
        const float g2 = gin[jj.z * GSTRIDE + lane];
        const float g3 = gin[jj.w * GSTRIDE + lane];
        acc = fmaf(f0, g0, fmaf(f1, g1, fmaf(f2, g2, fmaf(f3, g3, acc))));
    }
    for (; e < nn; ++e) {
        const int j = cols[i * CAP + e];
        const float f = vals[i * CAP + e] * rsqrtf(1.f + dcol[j]);
        acc = fmaf(f, gin[j * GSTRIDE + lane], acc);
    }
    return acc * di;
}

// ---- h = relu(spmm(gin)+bias); gout = h @ W. 4 rows/block, 1 row/wave. ----
__global__ __launch_bounds__(256) void k_layer(const float* __restrict__ gin,
                                               float* __restrict__ gout,
                                               const float* __restrict__ dcol,
                                               const int* __restrict__ cnt,
                                               const int* __restrict__ cols,
                                               const float* __restrict__ vals,
                                               const float* __restrict__ bias,
                                               const float* __restrict__ W) {
    __shared__ float hs[256];
    const int w = threadIdx.x >> 6, lane = threadIdx.x & 63;
    const int i = blockIdx.x * 4 + w;
    const float di = rsqrtf(1.f + dcol[i]);
    const float acc = spmm_row(gin, dcol, cnt, cols, vals, i, lane, di);
    float hv = 0.f;
    if (lane < NHID) hv = fmaxf(acc + bias[lane], 0.f);
    hs[w * 64 + lane] = hv;          // intra-wave only: no __syncthreads needed
    const int c = lane < NHID ? lane : 0;
    float o = 0.f;
    #pragma unroll 4
    for (int k = 0; k < NHID; ++k)
        o = fmaf(hs[w * 64 + k], W[k * NHID + c], o);   // LDS broadcast reads
    gout[i * GSTRIDE + lane] = (lane < NHID) ? o : 0.f;
}

// ---- h3 = spmm+b3; logits = h3@lin_w+lin_b; log_softmax over 4 classes ----
__global__ __launch_bounds__(256) void k_final(const float* __restrict__ gin,
                                               float* __restrict__ out,
                                               const float* __restrict__ dcol,
                                               const int* __restrict__ cnt,
                                               const int* __restrict__ cols,
                                               const float* __restrict__ vals,
                                               const float* __restrict__ b3,
                                               const float* __restrict__ lw,
                                               const float* __restrict__ lb) {
    __shared__ float hs[256];
    const int w = threadIdx.x >> 6, lane = threadIdx.x & 63;
    const int i = blockIdx.x * 4 + w;
    const float di = rsqrtf(1.f + dcol[i]);
    const float acc = spmm_row(gin, dcol, cnt, cols, vals, i, lane, di);
    hs[w * 64 + lane] = (lane < NHID) ? acc + b3[lane] : 0.f;   // intra-wave only
    if (lane < NCLASS) {
        float o = lb[lane];
        #pragma unroll 4
        for (int k = 0; k < NHID; ++k)
            o = fmaf(hs[w * 64 + k], lw[k * NCLASS + lane], o);
        float m = fmaxf(o, __shfl_xor(o, 1));
        m = fmaxf(m, __shfl_xor(m, 2));
        const float ex = __expf(o - m);
        float ss = ex + __shfl_xor(ex, 1);
        ss += __shfl_xor(ss, 2);
        out[i * NCLASS + lane] = o - m - __logf(ss);
    }
}

extern "C" void kernel_launch(void* const* d_in, const int* in_sizes, int n_in,
                              void* d_out, int out_size, void* d_ws, size_t ws_size,
                              hipStream_t stream) {
    const float* x   = (const float*)d_in[0];   // 4096 x 512
    const float* adj = (const float*)d_in[1];   // 4096 x 4096
    const float* P   = (const float*)d_in[2];   // 8390656
    const float* W1  = (const float*)d_in[3];   // 512 x 60
    const float* b1  = (const float*)d_in[4];
    const float* W2  = (const float*)d_in[5];   // 60 x 60
    const float* b2  = (const float*)d_in[6];
    const float* W3  = (const float*)d_in[7];   // 60 x 60
    const float* b3  = (const float*)d_in[8];
    const float* lw  = (const float*)d_in[9];   // 60 x 4
    const float* lb  = (const float*)d_in[10];
    float* out = (float*)d_out;                 // 4096 x 4

    char* ws = (char*)d_ws;
    float* dcol   = (float*)(ws);               // 16 KiB (zeroed)
    int*   cnt    = (int*)(ws + 16384);         // 16 KiB (zeroed)
    int*   qn     = (int*)(ws + 32768);         // 64 B   (zeroed)
    int*   equeue = (int*)(ws + 36864);         // 1 MiB edge id queue
    int*   cols   = (int*)(ws + 36864 + 1048576);                    // 1.5 MiB
    float* vals   = (float*)(ws + 36864 + 1048576 + 1572864);        // 1.5 MiB
    float* bufA   = (float*)(ws + 36864 + 1048576 + 2 * 1572864);            // 1 MiB
    float* bufB   = (float*)(ws + 36864 + 1048576 + 2 * 1572864 + 1048576);  // 1 MiB

    hipMemsetAsync(ws, 0, 36864, stream);       // zero dcol + cnt + qn

    k_scan    <<<SCAN_BLKS, 256, 0, stream>>>(adj, qn, equeue);
    k_edges_xw<<<XW_BLKS + EDGE_BLKS, 256, 0, stream>>>(P, qn, equeue, dcol, cnt,
                                                        cols, vals, x, W1, bufA);
    k_layer<<<NN / 4, 256, 0, stream>>>(bufA, bufB, dcol, cnt, cols, vals, b1, W2);
    k_layer<<<NN / 4, 256, 0, stream>>>(bufB, bufA, dcol, cnt, cols, vals, b2, W3);
    k_final<<<NN / 4, 256, 0, stream>>>(bufA, out, dcol, cnt, cols, vals, b3, lw, lb);
}

// Round 9
// 190.427 us; speedup vs baseline: 1.0834x; 1.0834x over previous
//
#include <hip/hip_runtime.h>
#include <math.h>

#define NN 4096
#define NFEAT 512
#define NHID 60
#define NCLASS 4
#define CAP 96        // per-row CSR capacity (mean ~8.2, statistical max ~22)
#define GSTRIDE 64    // padded hidden-state row stride
#define SCAN_BLKS 1024
#define SCAN_VPT 16   // float4 vectors per thread, all in flight at once
#define LQ_CAP 512    // per-block LDS edge queue (expected ~33/block)
#define XW_BLKS (NN / 4)                 // 1024
#define EDGE_BLKS 256                    // 65536 threads for ~33.5K edges

// ---- stage A: stream adj (16 batched loads/thread), compact edge ids ------
// All 16 loads issued back-to-back BEFORE any processing: nothing (branches,
// LDS atomics) sits between load issues, so the wave keeps 16 KB in flight.
__global__ __launch_bounds__(256) void k_scan(const float* __restrict__ adj,
                                              int* __restrict__ qn,
                                              int* __restrict__ equeue) {
    __shared__ int lq[LQ_CAP];
    __shared__ int lcnt, gbase;
    if (threadIdx.x == 0) lcnt = 0;
    __syncthreads();
    const int t = blockIdx.x * 256 + threadIdx.x;
    const uint4* adj4 = (const uint4*)adj;   // 0.0f/1.0f -> 0u/0x3f800000u
    uint4 a[SCAN_VPT];
    #pragma unroll
    for (int m = 0; m < SCAN_VPT; ++m)
        a[m] = adj4[m * (SCAN_BLKS * 256) + t];          // coalesced per pass
    #pragma unroll
    for (int m = 0; m < SCAN_VPT; ++m) {
        const uint4 v = a[m];
        if ((v.x | v.y | v.z | v.w) == 0u) continue;     // cheap any-test
        const unsigned av[4] = {v.x, v.y, v.z, v.w};
        const int e0 = (m * (SCAN_BLKS * 256) + t) * 4;
        #pragma unroll
        for (int q = 0; q < 4; ++q) {
            if (av[q] != 0u) {
                const int pos = atomicAdd(&lcnt, 1);     // LDS atomic: ~30cyc
                if (pos < LQ_CAP) lq[pos] = e0 + q;
            }
        }
    }
    __syncthreads();
    if (threadIdx.x == 0) gbase = atomicAdd(qn, lcnt);   // 1 global atomic/blk
    __syncthreads();
    const int n = min(lcnt, LQ_CAP);
    for (int k = threadIdx.x; k < n; k += 256)
        equeue[gbase + k] = lq[k];                       // coalesced flush
}

// ---- stage B: [0..1023] G1 = x@W1; [1024..1279] process queued edges ------
__global__ __launch_bounds__(256) void k_edges_xw(const float* __restrict__ P,
                                                  const int* __restrict__ qn,
                                                  const int* __restrict__ equeue,
                                                  float* __restrict__ dcol,
                                                  int* __restrict__ cnt,
                                                  int* __restrict__ cols,
                                                  float* __restrict__ vals,
                                                  const float* __restrict__ x,
                                                  const float* __restrict__ W1,
                                                  float* __restrict__ g1) {
    if (blockIdx.x >= XW_BLKS) {
        // ---- edges: one independent latency chain per thread --------------
        const int gtid = (blockIdx.x - XW_BLKS) * 256 + threadIdx.x;
        const int total = qn[0];
        for (int idx = gtid; idx < total; idx += EDGE_BLKS * 256) {
            const int e = equeue[idx];
            const int i = e >> 12;
            const int j = e & (NN - 1);
            const int hi = i > j ? i : j;
            const int lo = i > j ? j : i;
            const float pv = P[((hi * (hi + 1)) >> 1) + lo];
            const float s = 1.f / (1.f + __expf(-pv));     // sigmoid (adj==1)
            atomicAdd(&dcol[j], s);
            const int pos = atomicAdd(&cnt[i], 1);
            if (pos < CAP) { cols[i * CAP + pos] = j; vals[i * CAP + pos] = s; }
        }
    } else {
        // ---- xw: 4 rows/block, K split over 4 waves ------------------------
        __shared__ float part[1024];
        const int tid = threadIdx.x;
        const int w = tid >> 6, lane = tid & 63;
        const int c = lane < NHID ? lane : 0;
        const int row0 = blockIdx.x * 4;
        const int k0 = w * (NFEAT / 4);
        const float* x0 = x + (row0 + 0) * NFEAT;
        const float* x1 = x + (row0 + 1) * NFEAT;
        const float* x2 = x + (row0 + 2) * NFEAT;
        const float* x3 = x + (row0 + 3) * NFEAT;
        float a0 = 0.f, a1 = 0.f, a2 = 0.f, a3 = 0.f;
        for (int k = k0; k < k0 + NFEAT / 4; k += 4) {
            const float4 xv0 = *(const float4*)(x0 + k);   // wave-uniform 16B
            const float4 xv1 = *(const float4*)(x1 + k);
            const float4 xv2 = *(const float4*)(x2 + k);
            const float4 xv3 = *(const float4*)(x3 + k);
            const float w0 = W1[(k + 0) * NHID + c];       // lane-varying, L2-hot
            const float w1 = W1[(k + 1) * NHID + c];
            const float w2 = W1[(k + 2) * NHID + c];
            const float w3 = W1[(k + 3) * NHID + c];
            a0 = fmaf(xv0.x, w0, fmaf(xv0.y, w1, fmaf(xv0.z, w2, fmaf(xv0.w, w3, a0))));
            a1 = fmaf(xv1.x, w0, fmaf(xv1.y, w1, fmaf(xv1.z, w2, fmaf(xv1.w, w3, a1))));
            a2 = fmaf(xv2.x, w0, fmaf(xv2.y, w1, fmaf(xv2.z, w2, fmaf(xv2.w, w3, a2))));
            a3 = fmaf(xv3.x, w0, fmaf(xv3.y, w1, fmaf(xv3.z, w2, fmaf(xv3.w, w3, a3))));
        }
        part[(w * 4 + 0) * 64 + lane] = a0;
        part[(w * 4 + 1) * 64 + lane] = a1;
        part[(w * 4 + 2) * 64 + lane] = a2;
        part[(w * 4 + 3) * 64 + lane] = a3;
        __syncthreads();
        const float o = part[(0 * 4 + w) * 64 + lane] + part[(1 * 4 + w) * 64 + lane]
                      + part[(2 * 4 + w) * 64 + lane] + part[(3 * 4 + w) * 64 + lane];
        g1[(row0 + w) * GSTRIDE + lane] = (lane < NHID) ? o : 0.f;
    }
}

// ---- spmm edge accumulation, 4-batched for MLP ----------------------------
__device__ __forceinline__ float spmm_row(const float* __restrict__ gin,
                                          const float* __restrict__ dcol,
                                          const int* __restrict__ cnt,
                                          const int* __restrict__ cols,
                                          const float* __restrict__ vals,
                                          int i, int lane, float di) {
    const int nn = min(cnt[i], CAP);
    float acc = gin[i * GSTRIDE + lane] * di;   // self-loop term
    const int4*   c4 = (const int4*)(cols + i * CAP);
    const float4* v4 = (const float4*)(vals + i * CAP);
    int e = 0;
    for (; e + 4 <= nn; e += 4) {
        const int4   jj = c4[e >> 2];
        const float4 vv = v4[e >> 2];
        const float f0 = vv.x * rsqrtf(1.f + dcol[jj.x]);
        const float f1 = vv.y * rsqrtf(1.f + dcol[jj.y]);
        const float f2 = vv.z * rsqrtf(1.f + dcol[jj.z]);
        const float f3 = vv.w * rsqrtf(1.f + dcol[jj.w]);
        const float g0 = gin[jj.x * GSTRIDE + lane];
        const float g1 = gin[jj.y * GSTRIDE + lane];
        const float g2 = gin[jj.z * GSTRIDE + lane];
        const float g3 = gin[jj.w * GSTRIDE + lane];
        acc = fmaf(f0, g0, fmaf(f1, g1, fmaf(f2, g2, fmaf(f3, g3, acc))));
    }
    for (; e < nn; ++e) {
        const int j = cols[i * CAP + e];
        const float f = vals[i * CAP + e] * rsqrtf(1.f + dcol[j]);
        acc = fmaf(f, gin[j * GSTRIDE + lane], acc);
    }
    return acc * di;
}

// ---- h = relu(spmm(gin)+bias); gout = h @ W. 4 rows/block, 1 row/wave. ----
__global__ __launch_bounds__(256) void k_layer(const float* __restrict__ gin,
                                               float* __restrict__ gout,
                                               const float* __restrict__ dcol,
                                               const int* __restrict__ cnt,
                                               const int* __restrict__ cols,
                                               const float* __restrict__ vals,
                                               const float* __restrict__ bias,
                                               const float* __restrict__ W) {
    __shared__ float hs[256];
    const int w = threadIdx.x >> 6, lane = threadIdx.x & 63;
    const int i = blockIdx.x * 4 + w;
    const float di = rsqrtf(1.f + dcol[i]);
    const float acc = spmm_row(gin, dcol, cnt, cols, vals, i, lane, di);
    float hv = 0.f;
    if (lane < NHID) hv = fmaxf(acc + bias[lane], 0.f);
    hs[w * 64 + lane] = hv;          // intra-wave only: no __syncthreads needed
    const int c = lane < NHID ? lane : 0;
    float o = 0.f;
    #pragma unroll 4
    for (int k = 0; k < NHID; ++k)
        o = fmaf(hs[w * 64 + k], W[k * NHID + c], o);   // LDS broadcast reads
    gout[i * GSTRIDE + lane] = (lane < NHID) ? o : 0.f;
}

// ---- h3 = spmm+b3; logits = h3@lin_w+lin_b; log_softmax over 4 classes ----
__global__ __launch_bounds__(256) void k_final(const float* __restrict__ gin,
                                               float* __restrict__ out,
                                               const float* __restrict__ dcol,
                                               const int* __restrict__ cnt,
                                               const int* __restrict__ cols,
                                               const float* __restrict__ vals,
                                               const float* __restrict__ b3,
                                               const float* __restrict__ lw,
                                               const float* __restrict__ lb) {
    __shared__ float hs[256];
    const int w = threadIdx.x >> 6, lane = threadIdx.x & 63;
    const int i = blockIdx.x * 4 + w;
    const float di = rsqrtf(1.f + dcol[i]);
    const float acc = spmm_row(gin, dcol, cnt, cols, vals, i, lane, di);
    hs[w * 64 + lane] = (lane < NHID) ? acc + b3[lane] : 0.f;   // intra-wave only
    if (lane < NCLASS) {
        float o = lb[lane];
        #pragma unroll 4
        for (int k = 0; k < NHID; ++k)
            o = fmaf(hs[w * 64 + k], lw[k * NCLASS + lane], o);
        float m = fmaxf(o, __shfl_xor(o, 1));
        m = fmaxf(m, __shfl_xor(m, 2));
        const float ex = __expf(o - m);
        float ss = ex + __shfl_xor(ex, 1);
        ss += __shfl_xor(ss, 2);
        out[i * NCLASS + lane] = o - m - __logf(ss);
    }
}

extern "C" void kernel_launch(void* const* d_in, const int* in_sizes, int n_in,
                              void* d_out, int out_size, void* d_ws, size_t ws_size,
                              hipStream_t stream) {
    const float* x   = (const float*)d_in[0];   // 4096 x 512
    const float* adj = (const float*)d_in[1];   // 4096 x 4096
    const float* P   = (const float*)d_in[2];   // 8390656
    const float* W1  = (const float*)d_in[3];   // 512 x 60
    const float* b1  = (const float*)d_in[4];
    const float* W2  = (const float*)d_in[5];   // 60 x 60
    const float* b2  = (const float*)d_in[6];
    const float* W3  = (const float*)d_in[7];   // 60 x 60
    const float* b3  = (const float*)d_in[8];
    const float* lw  = (const float*)d_in[9];   // 60 x 4
    const float* lb  = (const float*)d_in[10];
    float* out = (float*)d_out;                 // 4096 x 4

    char* ws = (char*)d_ws;
    float* dcol   = (float*)(ws);               // 16 KiB (zeroed)
    int*   cnt    = (int*)(ws + 16384);         // 16 KiB (zeroed)
    int*   qn     = (int*)(ws + 32768);         // 64 B   (zeroed)
    int*   equeue = (int*)(ws + 36864);         // 1 MiB edge id queue
    int*   cols   = (int*)(ws + 36864 + 1048576);                    // 1.5 MiB
    float* vals   = (float*)(ws + 36864 + 1048576 + 1572864);        // 1.5 MiB
    float* bufA   = (float*)(ws + 36864 + 1048576 + 2 * 1572864);            // 1 MiB
    float* bufB   = (float*)(ws + 36864 + 1048576 + 2 * 1572864 + 1048576);  // 1 MiB

    hipMemsetAsync(ws, 0, 36864, stream);       // zero dcol + cnt + qn

    k_scan    <<<SCAN_BLKS, 256, 0, stream>>>(adj, qn, equeue);
    k_edges_xw<<<XW_BLKS + EDGE_BLKS, 256, 0, stream>>>(P, qn, equeue, dcol, cnt,
                                                        cols, vals, x, W1, bufA);
    k_layer<<<NN / 4, 256, 0, stream>>>(bufA, bufB, dcol, cnt, cols, vals, b1, W2);
    k_layer<<<NN / 4, 256, 0, stream>>>(bufB, bufA, dcol, cnt, cols, vals, b2, W3);
    k_final<<<NN / 4, 256, 0, stream>>>(bufA, out, dcol, cnt, cols, vals, b3, lw, lb);
}